// Round 1
// baseline (705.441 us; speedup 1.0000x reference)
//
#include <hip/hip_runtime.h>
#include <math.h>

#define NB   2048
#define CIN  192
#define HW   361
#define NTH  384   // 6 waves; one pixel per thread (361 active)

__device__ __forceinline__ float gelu_exact(float x) {
    return 0.5f * x * (1.0f + erff(x * 0.70710678118654752f));
}

__device__ __forceinline__ float wave_sum(float v) {
    #pragma unroll
    for (int o = 32; o >= 1; o >>= 1) v += __shfl_xor(v, o, 64);
    return v;
}

__device__ __forceinline__ float wave_max(float v) {
    #pragma unroll
    for (int o = 32; o >= 1; o >>= 1) v = fmaxf(v, __shfl_xor(v, o, 64));
    return v;
}

__global__ __launch_bounds__(NTH)
void policy_head_fused(const float* __restrict__ inputs,
                       const float* __restrict__ mask,
                       const float* __restrict__ mask_sum,
                       const float* __restrict__ w1p, const float* __restrict__ b1p,
                       const float* __restrict__ w1g, const float* __restrict__ b1g,
                       const float* __restrict__ beta_g,
                       const float* __restrict__ w_lin, const float* __restrict__ b_lin,
                       const float* __restrict__ beta2,
                       const float* __restrict__ w2p, const float* __restrict__ b2p,
                       float* __restrict__ out) {
    // LDS: combined conv1 weights [c][0..31]=w1p[:,c], [c][32..63]=w1g[:,c]
    __shared__ float wcomb[CIN * 64];          // 48 KiB
    __shared__ float small[160];               // b1p | b1g | beta_g | beta2 | w2p
    __shared__ float red_a[6 * 32];
    __shared__ float red_b[6 * 32];
    __shared__ float pooled[96];
    __shared__ float linout[32];

    const int tid = threadIdx.x;
    const int b   = blockIdx.x;

    // ---- stage weights into LDS ----
    for (int i = tid; i < CIN * 64; i += NTH) {
        int c = i >> 6, j = i & 63;
        wcomb[i] = (j < 32) ? w1p[j * CIN + c] : w1g[(j - 32) * CIN + c];
    }
    if (tid < 32)       small[tid] = b1p[tid];
    else if (tid < 64)  small[tid] = b1g[tid - 32];
    else if (tid < 96)  small[tid] = beta_g[tid - 64];
    else if (tid < 128) small[tid] = beta2[tid - 96];
    else if (tid < 160) small[tid] = w2p[tid - 128];
    __syncthreads();

    const int  hw  = tid;
    const bool act = (hw < HW);
    const int  hwc = act ? hw : (HW - 1);            // clamp so loads stay in-bounds
    const float m  = act ? mask[(size_t)b * HW + hw] : 0.f;
    const float ms = mask_sum[b];

    const float* xb = inputs + (size_t)b * (CIN * HW);

    // ---- conv1 (both heads): 64 fp32 accumulators per thread ----
    float accp[32], accg[32];
    #pragma unroll
    for (int i = 0; i < 32; ++i) { accp[i] = 0.f; accg[i] = 0.f; }

    #pragma unroll 2
    for (int c = 0; c < CIN; ++c) {
        float xc = xb[c * HW + hwc];
        const float4* wr = (const float4*)&wcomb[c * 64];
        #pragma unroll
        for (int i = 0; i < 8; ++i) {
            float4 w = wr[i];
            accp[4*i+0] = fmaf(xc, w.x, accp[4*i+0]);
            accp[4*i+1] = fmaf(xc, w.y, accp[4*i+1]);
            accp[4*i+2] = fmaf(xc, w.z, accp[4*i+2]);
            accp[4*i+3] = fmaf(xc, w.w, accp[4*i+3]);
        }
        #pragma unroll
        for (int i = 0; i < 8; ++i) {
            float4 w = wr[8 + i];
            accg[4*i+0] = fmaf(xc, w.x, accg[4*i+0]);
            accg[4*i+1] = fmaf(xc, w.y, accg[4*i+1]);
            accg[4*i+2] = fmaf(xc, w.z, accg[4*i+2]);
            accg[4*i+3] = fmaf(xc, w.w, accg[4*i+3]);
        }
    }

    // ---- g-head: mask, GELU, global pool (sum + max over 361 pixels) ----
    const int lane = tid & 63, wv = tid >> 6;
    const float off = (sqrtf(ms) - 28.0f) * 0.1f;

    #pragma unroll
    for (int g = 0; g < 32; ++g) {
        float v = (accg[g] + small[32 + g] + small[64 + g]) * m;  // (+b1g +beta_g)*mask
        v = gelu_exact(v);
        float sv = act ? v : 0.f;
        float mv = act ? (v + (m - 1.f)) : -1e30f;
        sv = wave_sum(sv);
        mv = wave_max(mv);
        if (lane == 0) { red_a[wv * 32 + g] = sv; red_b[wv * 32 + g] = mv; }
    }
    __syncthreads();

    if (tid < 32) {
        float s = 0.f, mx = -1e30f;
        #pragma unroll
        for (int w = 0; w < 6; ++w) {
            s += red_a[w * 32 + tid];
            mx = fmaxf(mx, red_b[w * 32 + tid]);
        }
        float mean = s / ms;
        pooled[tid]      = mean;
        pooled[32 + tid] = mean * off;
        pooled[64 + tid] = mx;
    }
    __syncthreads();

    if (tid < 32) {
        float a = b_lin[tid];
        #pragma unroll
        for (int j = 0; j < 96; ++j) a = fmaf(pooled[j], w_lin[tid * 96 + j], a);
        linout[tid] = a;
    }
    __syncthreads();

    // ---- p-head: add pooled bias, mask, GELU, 32->1 conv ----
    float acc2 = b2p[0];
    #pragma unroll
    for (int p = 0; p < 32; ++p) {
        float v = (accp[p] + small[p] + linout[p] + small[96 + p]) * m; // (+b1p+lin+beta2)*mask
        v = gelu_exact(v);
        acc2 = fmaf(v, small[128 + p], acc2);
    }
    float logit = acc2 - (1.f - m) * 5000.f;

    // ---- log-softmax over the 361 pixels ----
    float lg = act ? logit : -1e30f;
    float wmx = wave_max(lg);
    if (lane == 0) red_a[wv] = wmx;
    __syncthreads();
    float fmx = -1e30f;
    #pragma unroll
    for (int w = 0; w < 6; ++w) fmx = fmaxf(fmx, red_a[w]);

    float e  = act ? expf(lg - fmx) : 0.f;
    float ws = wave_sum(e);
    if (lane == 0) red_b[wv] = ws;
    __syncthreads();
    float tot = 0.f;
    #pragma unroll
    for (int w = 0; w < 6; ++w) tot += red_b[w];

    if (act) out[(size_t)b * HW + hw] = lg - fmx - logf(tot);
}

extern "C" void kernel_launch(void* const* d_in, const int* in_sizes, int n_in,
                              void* d_out, int out_size, void* d_ws, size_t ws_size,
                              hipStream_t stream) {
    const float* inputs   = (const float*)d_in[0];
    const float* mask     = (const float*)d_in[1];
    const float* mask_sum = (const float*)d_in[2];
    const float* w1p      = (const float*)d_in[3];
    const float* b1p      = (const float*)d_in[4];
    const float* w1g      = (const float*)d_in[5];
    const float* b1g      = (const float*)d_in[6];
    const float* beta_g   = (const float*)d_in[7];
    const float* w_lin    = (const float*)d_in[8];
    const float* b_lin    = (const float*)d_in[9];
    const float* beta2    = (const float*)d_in[10];
    const float* w2p      = (const float*)d_in[11];
    const float* b2p      = (const float*)d_in[12];
    float* out = (float*)d_out;

    policy_head_fused<<<dim3(NB), dim3(NTH), 0, stream>>>(
        inputs, mask, mask_sum, w1p, b1p, w1g, b1g, beta_g,
        w_lin, b_lin, beta2, w2p, b2p, out);
}

// Round 2
// 176.743 us; speedup vs baseline: 3.9913x; 3.9913x over previous
//
#include <hip/hip_runtime.h>
#include <math.h>

#define NB   2048
#define CIN  192
#define HW   361
#define NTH  512          // 8 waves; each wave owns 48 px (3 n-tiles of 16)
#define WPAD 200          // bf16 elems per LDS weight row (100 dwords -> 2-way = free)

typedef float f32x4 __attribute__((ext_vector_type(4)));
typedef short s16x8 __attribute__((ext_vector_type(8)));

__device__ __forceinline__ unsigned short f2bf(float f) {
    unsigned int u = __float_as_uint(f);
    u += 0x7FFFu + ((u >> 16) & 1u);          // round-to-nearest-even
    return (unsigned short)(u >> 16);
}

__device__ __forceinline__ float gelu_exact(float x) {
    return 0.5f * x * (1.0f + erff(x * 0.70710678118654752f));
}

__global__ __launch_bounds__(NTH)
void policy_head_mfma(const float* __restrict__ inputs,
                      const float* __restrict__ mask,
                      const float* __restrict__ mask_sum,
                      const float* __restrict__ w1p, const float* __restrict__ b1p,
                      const float* __restrict__ w1g, const float* __restrict__ b1g,
                      const float* __restrict__ beta_g,
                      const float* __restrict__ w_lin, const float* __restrict__ b_lin,
                      const float* __restrict__ beta2,
                      const float* __restrict__ w2p, const float* __restrict__ b2p,
                      float* __restrict__ out) {
    __shared__ unsigned short wlds[64 * WPAD];   // 25.6 KB bf16 weights (rows 0-31 w1p, 32-63 w1g)
    __shared__ float small[160];                 // b1p | b1g | beta_g | beta2 | w2p
    __shared__ float redA[32 * 8];
    __shared__ float redB[32 * 8];
    __shared__ float pooled[96];
    __shared__ float linout[32];

    const int tid = threadIdx.x;
    const int b   = blockIdx.x;

    // ---- stage conv1 weights (bf16) + small vectors into LDS ----
    for (int i = tid; i < 64 * CIN; i += NTH) {
        int o = i / CIN, c = i - o * CIN;
        float wv = (o < 32) ? w1p[o * CIN + c] : w1g[(o - 32) * CIN + c];
        wlds[o * WPAD + c] = f2bf(wv);
    }
    if (tid < 32)       small[tid] = b1p[tid];
    else if (tid < 64)  small[tid] = b1g[tid - 32];
    else if (tid < 96)  small[tid] = beta_g[tid - 64];
    else if (tid < 128) small[tid] = beta2[tid - 96];
    else if (tid < 160) small[tid] = w2p[tid - 128];
    __syncthreads();

    const int w    = tid >> 6;
    const int lane = tid & 63;
    const int g4   = lane >> 4;     // 0..3
    const int c16  = lane & 15;     // 0..15

    int   px[3], pxc[3];
    float mv[3];
    bool  valid[3];
    #pragma unroll
    for (int nt = 0; nt < 3; ++nt) {
        px[nt]    = w * 48 + nt * 16 + c16;
        valid[nt] = (px[nt] < HW);
        pxc[nt]   = valid[nt] ? px[nt] : (HW - 1);
        mv[nt]    = valid[nt] ? mask[(size_t)b * HW + px[nt]] : 0.f;
    }

    const float* xb = inputs + (size_t)b * (CIN * HW);

    // ---- conv1 via MFMA: D[o][px] = sum_c W[o][c] X[c][px] ----
    f32x4 acc[4][3];
    #pragma unroll
    for (int mt = 0; mt < 4; ++mt)
        #pragma unroll
        for (int nt = 0; nt < 3; ++nt)
            acc[mt][nt] = (f32x4){0.f, 0.f, 0.f, 0.f};

    for (int kk = 0; kk < 6; ++kk) {               // K = 192 = 6 x 32
        s16x8 a[4];
        #pragma unroll
        for (int mt = 0; mt < 4; ++mt)
            a[mt] = *(const s16x8*)&wlds[(mt * 16 + c16) * WPAD + kk * 32 + 8 * g4];

        #pragma unroll
        for (int nt = 0; nt < 3; ++nt) {
            const float* xp = xb + (size_t)(kk * 32 + 8 * g4) * HW + pxc[nt];
            float xv[8];
            #pragma unroll
            for (int i = 0; i < 8; ++i) xv[i] = xp[i * HW];
            s16x8 bf;
            #pragma unroll
            for (int i = 0; i < 8; ++i) bf[i] = (short)f2bf(xv[i]);
            #pragma unroll
            for (int mt = 0; mt < 4; ++mt)
                acc[mt][nt] = __builtin_amdgcn_mfma_f32_16x16x32_bf16(a[mt], bf, acc[mt][nt], 0, 0, 0);
        }
    }

    const float ms  = mask_sum[b];
    const float off = (sqrtf(ms) - 28.0f) * 0.1f;

    // ---- g-head: mask, GELU, pool (sum + max over px) ----
    #pragma unroll
    for (int mt = 2; mt < 4; ++mt) {
        #pragma unroll
        for (int r = 0; r < 4; ++r) {
            int og = (mt - 2) * 16 + g4 * 4 + r;              // 0..31
            float bb = small[32 + og] + small[64 + og];       // b1g + beta_g
            float s = 0.f, mx = -1e30f;
            #pragma unroll
            for (int nt = 0; nt < 3; ++nt) {
                float v = gelu_exact((acc[mt][nt][r] + bb) * mv[nt]);
                if (!valid[nt]) v = 0.f;
                s += v;
                float cand = valid[nt] ? (v + mv[nt] - 1.f) : -1e30f;
                mx = fmaxf(mx, cand);
            }
            #pragma unroll
            for (int o = 1; o < 16; o <<= 1) {
                s += __shfl_xor(s, o, 64);
                mx = fmaxf(mx, __shfl_xor(mx, o, 64));
            }
            if (c16 == 0) { redA[og * 8 + w] = s; redB[og * 8 + w] = mx; }
        }
    }
    __syncthreads();

    if (tid < 32) {
        float s = 0.f, mx = -1e30f;
        #pragma unroll
        for (int j = 0; j < 8; ++j) {
            s += redA[tid * 8 + j];
            mx = fmaxf(mx, redB[tid * 8 + j]);
        }
        float mean = s / ms;
        pooled[tid]      = mean;
        pooled[32 + tid] = mean * off;
        pooled[64 + tid] = mx;
    }
    __syncthreads();

    if (tid < 32) {
        float a = b_lin[tid];
        #pragma unroll
        for (int j = 0; j < 96; ++j) a = fmaf(pooled[j], w_lin[tid * 96 + j], a);
        linout[tid] = a;
    }
    __syncthreads();

    // ---- p-head: bias+lin+beta2, mask, GELU, dot with w2p ----
    float pv[3] = {0.f, 0.f, 0.f};
    #pragma unroll
    for (int mt = 0; mt < 2; ++mt) {
        #pragma unroll
        for (int r = 0; r < 4; ++r) {
            int op = mt * 16 + g4 * 4 + r;                    // 0..31
            float bb = small[op] + linout[op] + small[96 + op];
            float wo = small[128 + op];
            #pragma unroll
            for (int nt = 0; nt < 3; ++nt)
                pv[nt] += gelu_exact((acc[mt][nt][r] + bb) * mv[nt]) * wo;
        }
    }
    const float b2 = b2p[0];
    float logit[3];
    #pragma unroll
    for (int nt = 0; nt < 3; ++nt) {
        float t = pv[nt];
        t += __shfl_xor(t, 16, 64);
        t += __shfl_xor(t, 32, 64);
        logit[nt] = t + b2 - (1.f - mv[nt]) * 5000.f;
    }

    // ---- log-softmax over 361 px ----
    float lmax = -1e30f;
    #pragma unroll
    for (int nt = 0; nt < 3; ++nt)
        if (valid[nt]) lmax = fmaxf(lmax, logit[nt]);
    #pragma unroll
    for (int o = 1; o < 64; o <<= 1) lmax = fmaxf(lmax, __shfl_xor(lmax, o, 64));
    if (lane == 0) redA[w] = lmax;
    __syncthreads();
    float gmax = -1e30f;
    #pragma unroll
    for (int j = 0; j < 8; ++j) gmax = fmaxf(gmax, redA[j]);

    float es = 0.f;
    #pragma unroll
    for (int nt = 0; nt < 3; ++nt)
        if (valid[nt] && g4 == 0) es += expf(logit[nt] - gmax);
    #pragma unroll
    for (int o = 1; o < 64; o <<= 1) es += __shfl_xor(es, o, 64);
    if (lane == 0) redB[w] = es;
    __syncthreads();
    float tot = 0.f;
    #pragma unroll
    for (int j = 0; j < 8; ++j) tot += redB[j];
    const float lt = logf(tot) + gmax;

    if (g4 == 0) {
        #pragma unroll
        for (int nt = 0; nt < 3; ++nt)
            if (valid[nt]) out[(size_t)b * HW + px[nt]] = logit[nt] - lt;
    }
}

extern "C" void kernel_launch(void* const* d_in, const int* in_sizes, int n_in,
                              void* d_out, int out_size, void* d_ws, size_t ws_size,
                              hipStream_t stream) {
    const float* inputs   = (const float*)d_in[0];
    const float* mask     = (const float*)d_in[1];
    const float* mask_sum = (const float*)d_in[2];
    const float* w1p      = (const float*)d_in[3];
    const float* b1p      = (const float*)d_in[4];
    const float* w1g      = (const float*)d_in[5];
    const float* b1g      = (const float*)d_in[6];
    const float* beta_g   = (const float*)d_in[7];
    const float* w_lin    = (const float*)d_in[8];
    const float* b_lin    = (const float*)d_in[9];
    const float* beta2    = (const float*)d_in[10];
    const float* w2p      = (const float*)d_in[11];
    const float* b2p      = (const float*)d_in[12];
    float* out = (float*)d_out;

    policy_head_mfma<<<dim3(NB), dim3(NTH), 0, stream>>>(
        inputs, mask, mask_sum, w1p, b1p, w1g, b1g, beta_g,
        w_lin, b_lin, beta2, w2p, b2p, out);
}

// Round 3
// 156.667 us; speedup vs baseline: 4.5028x; 1.1281x over previous
//
#include <hip/hip_runtime.h>
#include <hip/hip_bf16.h>
#include <math.h>

#define NB   2048
#define CIN  192
#define HW   361
#define NTH  512          // 8 waves; each wave owns 48 px (3 n-tiles of 16)
#define WPAD 200          // bf16 elems per LDS weight row (100 dwords -> 2-way = free)

typedef float f32x4 __attribute__((ext_vector_type(4)));
typedef short s16x8 __attribute__((ext_vector_type(8)));

__device__ __forceinline__ short f2bf_bits(float f) {
    __hip_bfloat16 h = __float2bfloat16(f);   // RNE; pairs fuse to v_cvt_pk_bf16_f32
    short s;
    __builtin_memcpy(&s, &h, sizeof(s));
    return s;
}

// tanh-form GELU via hardware exp: x * e/(e+1), e = exp(1.59577*(x + 0.044715 x^3))
__device__ __forceinline__ float gelu_fast(float x) {
    float inner = x * fmaf(0.044715f, x * x, 1.0f);
    float t = 1.5957691216057308f * inner;
    if (t > 40.f) return x;                   // overflow guard
    float e = __expf(t);
    return x * (e / (e + 1.0f));
}

__global__ __launch_bounds__(NTH, 4)   // cap VGPR at 128 -> 2 blocks/CU
void policy_head_mfma(const float* __restrict__ inputs,
                      const float* __restrict__ mask,
                      const float* __restrict__ mask_sum,
                      const float* __restrict__ w1p, const float* __restrict__ b1p,
                      const float* __restrict__ w1g, const float* __restrict__ b1g,
                      const float* __restrict__ beta_g,
                      const float* __restrict__ w_lin, const float* __restrict__ b_lin,
                      const float* __restrict__ beta2,
                      const float* __restrict__ w2p, const float* __restrict__ b2p,
                      float* __restrict__ out) {
    __shared__ unsigned short wlds[64 * WPAD];   // 25.6 KB bf16 weights
    __shared__ float small[160];                 // b1p | b1g | beta_g | beta2 | w2p
    __shared__ float redA[32 * 8];
    __shared__ float redB[32 * 8];
    __shared__ float pooled[96];
    __shared__ float linout[32];

    const int tid = threadIdx.x;
    const int b   = blockIdx.x;

    // ---- stage conv1 weights (bf16) + small vectors into LDS ----
    for (int i = tid; i < 64 * CIN; i += NTH) {
        int o = i / CIN, c = i - o * CIN;
        float wv = (o < 32) ? w1p[o * CIN + c] : w1g[(o - 32) * CIN + c];
        wlds[o * WPAD + c] = (unsigned short)f2bf_bits(wv);
    }
    if (tid < 32)       small[tid] = b1p[tid];
    else if (tid < 64)  small[tid] = b1g[tid - 32];
    else if (tid < 96)  small[tid] = beta_g[tid - 64];
    else if (tid < 128) small[tid] = beta2[tid - 96];
    else if (tid < 160) small[tid] = w2p[tid - 128];
    __syncthreads();

    const int w    = tid >> 6;
    const int lane = tid & 63;
    const int g4   = lane >> 4;     // 0..3
    const int c16  = lane & 15;     // 0..15
    const int krow = 8 * g4;

    int   px[3], pxc[3];
    float mv[3];
    bool  valid[3];
    #pragma unroll
    for (int nt = 0; nt < 3; ++nt) {
        px[nt]    = w * 48 + nt * 16 + c16;
        valid[nt] = (px[nt] < HW);
        pxc[nt]   = valid[nt] ? px[nt] : (HW - 1);
        mv[nt]    = valid[nt] ? mask[(size_t)b * HW + px[nt]] : 0.f;
    }

    const float* xb = inputs + (size_t)b * (CIN * HW);

    auto loadx = [&](float (&xv)[3][8], int kk) {
        const float* xk = xb + (size_t)(kk * 32 + krow) * HW;
        #pragma unroll
        for (int nt = 0; nt < 3; ++nt) {
            const float* xp = xk + pxc[nt];
            #pragma unroll
            for (int i = 0; i < 8; ++i) xv[nt][i] = xp[i * HW];
        }
    };

    // ---- conv1 via MFMA with 1-deep prefetch ----
    f32x4 acc[4][3];
    #pragma unroll
    for (int mt = 0; mt < 4; ++mt)
        #pragma unroll
        for (int nt = 0; nt < 3; ++nt)
            acc[mt][nt] = (f32x4){0.f, 0.f, 0.f, 0.f};

    float xv[3][8];
    loadx(xv, 0);

    for (int kk = 0; kk < 6; ++kk) {
        // consume xv into bf16 fragments (frees xv registers)
        s16x8 bfr[3];
        #pragma unroll
        for (int nt = 0; nt < 3; ++nt)
            #pragma unroll
            for (int i = 0; i < 8; ++i)
                bfr[nt][i] = f2bf_bits(xv[nt][i]);

        // issue next iteration's loads BEFORE the MFMAs
        int kkn = (kk < 5) ? kk + 1 : 0;
        loadx(xv, kkn);

        s16x8 a[4];
        #pragma unroll
        for (int mt = 0; mt < 4; ++mt)
            a[mt] = *(const s16x8*)&wlds[(mt * 16 + c16) * WPAD + kk * 32 + krow];

        #pragma unroll
        for (int nt = 0; nt < 3; ++nt)
            #pragma unroll
            for (int mt = 0; mt < 4; ++mt)
                acc[mt][nt] = __builtin_amdgcn_mfma_f32_16x16x32_bf16(a[mt], bfr[nt], acc[mt][nt], 0, 0, 0);
    }

    const float ms  = mask_sum[b];
    const float off = (sqrtf(ms) - 28.0f) * 0.1f;

    // ---- g-head: mask, GELU, pool (sum + max over px) ----
    #pragma unroll
    for (int mt = 2; mt < 4; ++mt) {
        #pragma unroll
        for (int r = 0; r < 4; ++r) {
            int og = (mt - 2) * 16 + g4 * 4 + r;              // 0..31
            float bb = small[32 + og] + small[64 + og];       // b1g + beta_g
            float s = 0.f, mx = -1e30f;
            #pragma unroll
            for (int nt = 0; nt < 3; ++nt) {
                float v = gelu_fast((acc[mt][nt][r] + bb) * mv[nt]);
                if (!valid[nt]) v = 0.f;
                s += v;
                float cand = valid[nt] ? (v + mv[nt] - 1.f) : -1e30f;
                mx = fmaxf(mx, cand);
            }
            #pragma unroll
            for (int o = 1; o < 16; o <<= 1) {
                s += __shfl_xor(s, o, 64);
                mx = fmaxf(mx, __shfl_xor(mx, o, 64));
            }
            if (c16 == 0) { redA[og * 8 + w] = s; redB[og * 8 + w] = mx; }
        }
    }
    __syncthreads();

    if (tid < 32) {
        float s = 0.f, mx = -1e30f;
        #pragma unroll
        for (int j = 0; j < 8; ++j) {
            s += redA[tid * 8 + j];
            mx = fmaxf(mx, redB[tid * 8 + j]);
        }
        float mean = s / ms;
        pooled[tid]      = mean;
        pooled[32 + tid] = mean * off;
        pooled[64 + tid] = mx;
    }
    __syncthreads();

    if (tid < 32) {
        float a = b_lin[tid];
        #pragma unroll
        for (int j = 0; j < 96; ++j) a = fmaf(pooled[j], w_lin[tid * 96 + j], a);
        linout[tid] = a;
    }
    __syncthreads();

    // ---- p-head: bias+lin+beta2, mask, GELU, dot with w2p ----
    float pv[3] = {0.f, 0.f, 0.f};
    #pragma unroll
    for (int mt = 0; mt < 2; ++mt) {
        #pragma unroll
        for (int r = 0; r < 4; ++r) {
            int op = mt * 16 + g4 * 4 + r;                    // 0..31
            float bb = small[op] + linout[op] + small[96 + op];
            float wo = small[128 + op];
            #pragma unroll
            for (int nt = 0; nt < 3; ++nt)
                pv[nt] += gelu_fast((acc[mt][nt][r] + bb) * mv[nt]) * wo;
        }
    }
    const float b2 = b2p[0];
    float logit[3];
    #pragma unroll
    for (int nt = 0; nt < 3; ++nt) {
        float t = pv[nt];
        t += __shfl_xor(t, 16, 64);
        t += __shfl_xor(t, 32, 64);
        logit[nt] = t + b2 - (1.f - mv[nt]) * 5000.f;
    }

    // ---- log-softmax over 361 px ----
    float lmax = -1e30f;
    #pragma unroll
    for (int nt = 0; nt < 3; ++nt)
        if (valid[nt]) lmax = fmaxf(lmax, logit[nt]);
    #pragma unroll
    for (int o = 1; o < 64; o <<= 1) lmax = fmaxf(lmax, __shfl_xor(lmax, o, 64));
    if (lane == 0) redA[w] = lmax;
    __syncthreads();
    float gmax = -1e30f;
    #pragma unroll
    for (int j = 0; j < 8; ++j) gmax = fmaxf(gmax, redA[j]);

    float es = 0.f;
    #pragma unroll
    for (int nt = 0; nt < 3; ++nt)
        if (valid[nt] && g4 == 0) es += __expf(logit[nt] - gmax);
    #pragma unroll
    for (int o = 1; o < 64; o <<= 1) es += __shfl_xor(es, o, 64);
    if (lane == 0) redB[w] = es;
    __syncthreads();
    float tot = 0.f;
    #pragma unroll
    for (int j = 0; j < 8; ++j) tot += redB[j];
    const float lt = __logf(tot) + gmax;

    if (g4 == 0) {
        #pragma unroll
        for (int nt = 0; nt < 3; ++nt)
            if (valid[nt]) out[(size_t)b * HW + px[nt]] = logit[nt] - lt;
    }
}

extern "C" void kernel_launch(void* const* d_in, const int* in_sizes, int n_in,
                              void* d_out, int out_size, void* d_ws, size_t ws_size,
                              hipStream_t stream) {
    const float* inputs   = (const float*)d_in[0];
    const float* mask     = (const float*)d_in[1];
    const float* mask_sum = (const float*)d_in[2];
    const float* w1p      = (const float*)d_in[3];
    const float* b1p      = (const float*)d_in[4];
    const float* w1g      = (const float*)d_in[5];
    const float* b1g      = (const float*)d_in[6];
    const float* beta_g   = (const float*)d_in[7];
    const float* w_lin    = (const float*)d_in[8];
    const float* b_lin    = (const float*)d_in[9];
    const float* beta2    = (const float*)d_in[10];
    const float* w2p      = (const float*)d_in[11];
    const float* b2p      = (const float*)d_in[12];
    float* out = (float*)d_out;

    policy_head_mfma<<<dim3(NB), dim3(NTH), 0, stream>>>(
        inputs, mask, mask_sum, w1p, b1p, w1g, b1g, beta_g,
        w_lin, b_lin, beta2, w2p, b2p, out);
}